// Round 4
// baseline (336.294 us; speedup 1.0000x reference)
//
#include <hip/hip_runtime.h>
#include <math.h>

#define NBINS 256

// Per-lane private u16 histograms in LDS: lh[bin*64 + lane]. No atomics.
// Bank: dword = bin*32 + lane/2 -> exactly 2 lanes/bank (free per m136).
// Binning matches reference f32 math: floor((x+1)/width) == trunc((x+1)*128)
// since width = 2/256 is a power of two and x+1 >= 0; clip to 255; ignore
// out-of-range (NaN fails both compares, contributing 0 as in the reference).
__global__ __launch_bounds__(64) void hist2_kernel(const float* __restrict__ a,
                                                   const float* __restrict__ b,
                                                   unsigned int* __restrict__ ghist,
                                                   int n4a, int n4b, int na, int nb,
                                                   int half_blocks) {
    __shared__ unsigned short lh[NBINS * 64];  // 32 KB
    const int lane = threadIdx.x;

    // zero-init: 32768 B = 2048 uint4 -> 32 iterations of 64 lanes
    uint4* z = (uint4*)lh;
#pragma unroll
    for (int k = 0; k < 32; k++) z[lane + 64 * k] = make_uint4(0u, 0u, 0u, 0u);
    __syncthreads();

    const int which = (blockIdx.x >= half_blocks) ? 1 : 0;
    const float4* __restrict__ x4 = (const float4*)(which ? b : a);
    const float* __restrict__ x1 = which ? b : a;
    const int n4 = which ? n4b : n4a;
    const int n = which ? nb : na;
    const int bid = which ? (blockIdx.x - half_blocks) : blockIdx.x;
    const int stride = half_blocks * 64;

#define BIN1(f)                                              \
    do {                                                     \
        float _f = (f);                                      \
        if (_f >= -1.0f && _f <= 1.0f) {                     \
            int _bin = (int)((_f + 1.0f) * 128.0f);          \
            _bin = _bin > (NBINS - 1) ? (NBINS - 1) : _bin;  \
            int _idx = (_bin << 6) + lane;                   \
            lh[_idx] = (unsigned short)(lh[_idx] + 1);       \
        }                                                    \
    } while (0)

#define BIN4(v) do { BIN1((v).x); BIN1((v).y); BIN1((v).z); BIN1((v).w); } while (0)

    int i = bid * 64 + lane;
    // 8 independent float4 loads in flight per wave before the LDS RMW chain
    for (; i + 7 * stride < n4; i += 8 * stride) {
        float4 v0 = x4[i];
        float4 v1 = x4[i + stride];
        float4 v2 = x4[i + 2 * stride];
        float4 v3 = x4[i + 3 * stride];
        float4 v4 = x4[i + 4 * stride];
        float4 v5 = x4[i + 5 * stride];
        float4 v6 = x4[i + 6 * stride];
        float4 v7 = x4[i + 7 * stride];
        BIN4(v0); BIN4(v1); BIN4(v2); BIN4(v3);
        BIN4(v4); BIN4(v5); BIN4(v6); BIN4(v7);
    }
    for (; i < n4; i += stride) {
        float4 v = x4[i];
        BIN4(v);
    }
    // scalar tail (n % 4) — no-op for this problem's sizes
    for (int t = n4 * 4 + bid * 64 + lane; t < n; t += stride) BIN1(x1[t]);

    __syncthreads();

    // Fold 64 lanes per bin. Thread handles bins lane+64k; lane-staggered
    // dword reads -> bank = (jj+lane)%32, 2 lanes/bank (free).
    const unsigned int* lhd = (const unsigned int*)lh;
#pragma unroll
    for (int k = 0; k < 4; k++) {
        const int bin = lane + (k << 6);
        unsigned int lo = 0, hi = 0;
#pragma unroll
        for (int jj = 0; jj < 32; jj++) {
            const int j = (jj + lane) & 31;
            const unsigned int v = lhd[(bin << 5) + j];
            lo += v & 0xFFFFu;
            hi += v >> 16;
        }
        atomicAdd(&ghist[(which << 8) + bin], lo + hi);
    }
}

// Entropy of both histograms + |diff|, all in double. One block of 256 threads.
__global__ __launch_bounds__(256) void entropy_kernel(const unsigned int* __restrict__ gh,
                                                      float* __restrict__ out) {
    __shared__ double sd[NBINS];
    const int tid = threadIdx.x;
    double e[2];

    for (int h = 0; h < 2; h++) {
        const double hv = (double)gh[h * NBINS + tid];

        sd[tid] = hv;
        __syncthreads();
        for (int o = 128; o > 0; o >>= 1) {
            if (tid < o) sd[tid] += sd[tid + o];
            __syncthreads();
        }
        const double total = sd[0];
        __syncthreads();

        const double p = hv / total + 1e-8;
        sd[tid] = -p * log(p);
        __syncthreads();
        for (int o = 128; o > 0; o >>= 1) {
            if (tid < o) sd[tid] += sd[tid + o];
            __syncthreads();
        }
        e[h] = sd[0];
        __syncthreads();
    }

    if (tid == 0) out[0] = (float)fabs(e[0] - e[1]);
}

extern "C" void kernel_launch(void* const* d_in, const int* in_sizes, int n_in,
                              void* d_out, int out_size, void* d_ws, size_t ws_size,
                              hipStream_t stream) {
    const float* pred = (const float*)d_in[0];
    const float* gt   = (const float*)d_in[1];
    const int n0 = in_sizes[0];
    const int n1 = in_sizes[1];

    unsigned int* hist = (unsigned int*)d_ws;  // [2][NBINS]
    hipMemsetAsync(d_ws, 0, 2 * NBINS * sizeof(unsigned int), stream);

    // 64-thread blocks, 32 KB LDS -> 5 blocks/CU; 640 blocks per input
    // = 1280 total = exactly 5/CU in a single occupancy round.
    const int half_blocks = 640;
    hist2_kernel<<<2 * half_blocks, 64, 0, stream>>>(pred, gt, hist,
                                                     n0 / 4, n1 / 4, n0, n1,
                                                     half_blocks);
    entropy_kernel<<<1, 256, 0, stream>>>(hist, (float*)d_out);
}

// Round 5
// 334.546 us; speedup vs baseline: 1.0052x; 1.0052x over previous
//
#include <hip/hip_runtime.h>
#include <math.h>

#define NBINS 256
#define TRASH 255  // LDS row 255 = garbage absorber (dups + out-of-range); real bin 255 lives in a VGPR

// Per-lane private u16 histograms in LDS: lh[row*64 + lane] (2 lanes/bank, free).
// Batched RMW: 4 reads -> 1 wait -> 4 writes per float4, with in-register dedup
// so all live targets in a batch are distinct (duplicates merge into the first
// occurrence; merged/out-of-range elements redirect to the trash row, whose
// contents are never read as data). Inter-batch RAW is safe: DS ops execute in
// program order within a wave (verified by R4 passing correctness).
__global__ __launch_bounds__(64) void hist2_kernel(const float* __restrict__ a,
                                                   const float* __restrict__ b,
                                                   unsigned int* __restrict__ ghist,
                                                   int n4a, int n4b, int na, int nb,
                                                   int half_blocks) {
#pragma clang fp contract(off)
    __shared__ unsigned short lh[NBINS * 64];  // 32 KB
    const int lane = threadIdx.x;

    uint4* z = (uint4*)lh;  // 2048 uint4 / 64 lanes = 32 iters
#pragma unroll
    for (int k = 0; k < 32; k++) z[lane + 64 * k] = make_uint4(0u, 0u, 0u, 0u);
    __syncthreads();

    const int which = (blockIdx.x >= half_blocks) ? 1 : 0;
    const float4* __restrict__ x4 = (const float4*)(which ? b : a);
    const float* __restrict__ x1 = which ? b : a;
    const int n4 = which ? n4b : n4a;
    const int n = which ? nb : na;
    const int bid = which ? (blockIdx.x - half_blocks) : blockIdx.x;
    const int stride = half_blocks * 64;
    unsigned int r255 = 0;  // real bin-255 counter (row 255 is trash)

// row = bin for in-range (bin 255 -> trash, counted in r255), TRASH otherwise.
// (f+1) rounded then *128 exact == reference's (x - lo)/width with width=2^-7.
#define ROWOF(f, rowv)                                            \
    {                                                             \
        float _u = ((f) + 1.0f) * 128.0f;                         \
        int _bi = (int)_u;                                        \
        _bi = _bi > 255 ? 255 : _bi;                              \
        bool _in = ((f) >= -1.0f) & ((f) <= 1.0f);                \
        r255 += (_in & (_bi == 255)) ? 1u : 0u;                   \
        rowv = _in ? _bi : TRASH;                                 \
    }

#define BATCH4(v)                                                                 \
    {                                                                             \
        int r0, r1, r2, r3;                                                       \
        ROWOF((v).x, r0) ROWOF((v).y, r1) ROWOF((v).z, r2) ROWOF((v).w, r3)       \
        int e01 = (r1 == r0), e02 = (r2 == r0), e12 = (r2 == r1);                 \
        int e03 = (r3 == r0), e13 = (r3 == r1), e23 = (r3 == r2);                 \
        int c0 = 1 + e01 + e02 + e03;                                             \
        int c1 = 1 + e12 + e13;                                                   \
        int c2 = 1 + e23;                                                         \
        int w1 = e01 ? TRASH : r1;                                                \
        int w2 = (e02 | e12) ? TRASH : r2;                                        \
        int w3 = (e03 | e13 | e23) ? TRASH : r3;                                  \
        int i0 = (r0 << 6) | lane, i1 = (w1 << 6) | lane;                         \
        int i2 = (w2 << 6) | lane, i3 = (w3 << 6) | lane;                         \
        unsigned short v0 = lh[i0], v1 = lh[i1], v2 = lh[i2], v3 = lh[i3];        \
        lh[i0] = (unsigned short)(v0 + c0);                                       \
        lh[i1] = (unsigned short)(v1 + c1);                                       \
        lh[i2] = (unsigned short)(v2 + c2);                                       \
        lh[i3] = (unsigned short)(v3 + 1);                                        \
    }

    int i = bid * 64 + lane;
    for (; i + 7 * stride < n4; i += 8 * stride) {
        float4 v0 = x4[i];
        float4 v1 = x4[i + stride];
        float4 v2 = x4[i + 2 * stride];
        float4 v3 = x4[i + 3 * stride];
        float4 v4 = x4[i + 4 * stride];
        float4 v5 = x4[i + 5 * stride];
        float4 v6 = x4[i + 6 * stride];
        float4 v7 = x4[i + 7 * stride];
        BATCH4(v0) BATCH4(v1) BATCH4(v2) BATCH4(v3)
        BATCH4(v4) BATCH4(v5) BATCH4(v6) BATCH4(v7)
    }
    for (; i < n4; i += stride) {
        float4 v = x4[i];
        BATCH4(v)
    }
    // scalar tail (n % 4 != 0) — unused for this problem's sizes
    for (int t = n4 * 4 + bid * 64 + lane; t < n; t += stride) {
        int r;
        ROWOF(x1[t], r)
        int idx = (r << 6) | lane;
        lh[idx] = (unsigned short)(lh[idx] + 1);
    }

    __syncthreads();

    // Fold bins 0..254 (row 255 is garbage). Lane-staggered dword reads:
    // bank = (jj+lane)%32, 2 lanes/bank (free).
    const unsigned int* lhd = (const unsigned int*)lh;
#pragma unroll
    for (int k = 0; k < 4; k++) {
        const int bin = lane + (k << 6);
        if (bin < 255) {
            unsigned int lo = 0, hi = 0;
#pragma unroll
            for (int jj = 0; jj < 32; jj++) {
                const int j = (jj + lane) & 31;
                const unsigned int v = lhd[(bin << 5) + j];
                lo += v & 0xFFFFu;
                hi += v >> 16;
            }
            atomicAdd(&ghist[(which << 8) + bin], lo + hi);
        }
    }
    // bin 255: wave-reduce the VGPR counters
    unsigned int s = r255;
#pragma unroll
    for (int o = 32; o > 0; o >>= 1) s += __shfl_down(s, o, 64);
    if (lane == 0 && s) atomicAdd(&ghist[(which << 8) + 255], s);
}

// Entropy of both histograms + |diff|, all in double. One block of 256 threads.
__global__ __launch_bounds__(256) void entropy_kernel(const unsigned int* __restrict__ gh,
                                                      float* __restrict__ out) {
    __shared__ double sd[NBINS];
    const int tid = threadIdx.x;
    double e[2];

    for (int h = 0; h < 2; h++) {
        const double hv = (double)gh[h * NBINS + tid];

        sd[tid] = hv;
        __syncthreads();
        for (int o = 128; o > 0; o >>= 1) {
            if (tid < o) sd[tid] += sd[tid + o];
            __syncthreads();
        }
        const double total = sd[0];
        __syncthreads();

        const double p = hv / total + 1e-8;
        sd[tid] = -p * log(p);
        __syncthreads();
        for (int o = 128; o > 0; o >>= 1) {
            if (tid < o) sd[tid] += sd[tid + o];
            __syncthreads();
        }
        e[h] = sd[0];
        __syncthreads();
    }

    if (tid == 0) out[0] = (float)fabs(e[0] - e[1]);
}

extern "C" void kernel_launch(void* const* d_in, const int* in_sizes, int n_in,
                              void* d_out, int out_size, void* d_ws, size_t ws_size,
                              hipStream_t stream) {
    const float* pred = (const float*)d_in[0];
    const float* gt   = (const float*)d_in[1];
    const int n0 = in_sizes[0];
    const int n1 = in_sizes[1];

    unsigned int* hist = (unsigned int*)d_ws;  // [2][NBINS]
    hipMemsetAsync(d_ws, 0, 2 * NBINS * sizeof(unsigned int), stream);

    // 64-thread blocks, 32 KB LDS -> 5 blocks/CU; 640 blocks/input = one full
    // residency round (1280 total).
    const int half_blocks = 640;
    hist2_kernel<<<2 * half_blocks, 64, 0, stream>>>(pred, gt, hist,
                                                     n0 / 4, n1 / 4, n0, n1,
                                                     half_blocks);
    entropy_kernel<<<1, 256, 0, stream>>>(hist, (float*)d_out);
}